// Round 8
// baseline (132.969 us; speedup 1.0000x reference)
//
#include <hip/hip_runtime.h>
#include <math.h>

#define NG   512
#define NPER 256
#define DD   128
#define EPER 4096
#define KK   128
#define NT   512
#define NW   8      // waves per block

// Opaque register pin (keeps x on-chip; compiler may use AGPRs - fine).
#define KEEP4(v) asm volatile("" : "+v"(v.x), "+v"(v.y), "+v"(v.z), "+v"(v.w))

// Monotonic float<->u32 key for atomicMax-based float max.
__device__ __forceinline__ unsigned fkey(float f) {
  int i = __float_as_int(f);
  return (unsigned)(i ^ ((i >> 31) | 0x80000000));
}
__device__ __forceinline__ float funkey(unsigned k) {
  int i = (k & 0x80000000u) ? (int)(k ^ 0x80000000u) : ~(int)k;
  return __int_as_float(i);
}

__global__ __launch_bounds__(NT, 4) void sag_fused(
    const float* __restrict__ x,      // [N, 128] f32
    const int*   __restrict__ esrc,   // [E]
    const int*   __restrict__ edst,   // [E]
    const float* __restrict__ gcn_w,  // [128]
    const float* __restrict__ gcn_b,  // [1]
    const float* __restrict__ lin_w,  // [256, 128]
    const float* __restrict__ lin_b,  // [128]
    float* __restrict__ out)          // [512, 128]
{
  const int g    = blockIdx.x;
  const int tid  = threadIdx.x;
  const int lane = tid & 63;
  const int wave = tid >> 6;
  const int j    = lane & 15;          // dim-group within 16-lane group
  const int sub  = lane >> 4;          // 0..3

  __shared__ int      sDeg[NPER];
  __shared__ int      sRank[NPER];
  __shared__ float    sXW[NPER];       // raw xw
  __shared__ float4   sScore4[NPER / 4];
  __shared__ float    sGate[NPER];
  __shared__ float    sMean[DD];       // atomic sum accumulators
  __shared__ unsigned sMaxK[DD];       // atomic max accumulators (keyed)
  __shared__ float    sOut[DD];        // atomic matvec accumulators
  float* sScore = (float*)sScore4;

  // ---- Edge loads FIRST (B1 will drain only these)
  const int4* es4 = (const int4*)(esrc + (size_t)g * EPER);
  const int4* ed4 = (const int4*)(edst + (size_t)g * EPER);
  int4 sa = es4[tid], sb = es4[NT + tid];
  int4 da = ed4[tid], db = ed4[NT + tid];

  // ---- Init (constants only - no data dependence)
  if (tid < NPER) { sDeg[tid] = 1; sRank[tid] = 0; sScore[tid] = 0.0f; }
  if (tid < DD)   { sMean[tid] = 0.0f; sMaxK[tid] = 0x007FFFFFu; sOut[tid] = 0.0f; }
  __syncthreads();                                      // B1 (drains edges only)

  // ---- x + w loads issued AFTER B1: drain overlaps degree + P1 start
  const float4* xg4 = (const float4*)(x + (size_t)g * NPER * DD);
  const int colbase = (wave * 4 + sub) * 32 + j;
  float4 q0[8], q1[8];
  #pragma unroll
  for (int r = 0; r < 8; ++r) {
    q0[r] = xg4[r * 1024 + colbase];          // node r*32+wave*4+sub, dims [4j,4j+4)
    q1[r] = xg4[r * 1024 + colbase + 16];     // dims [64+4j, 64+4j+4)
  }
  float4 wa = ((const float4*)gcn_w)[j];
  float4 wb = ((const float4*)gcn_w)[16 + j];

  // ---- Degree atomics (edge regs already drained at B1; x still in flight)
  atomicAdd(&sDeg[da.x & 255], 1);
  atomicAdd(&sDeg[da.y & 255], 1);
  atomicAdd(&sDeg[da.z & 255], 1);
  atomicAdd(&sDeg[da.w & 255], 1);
  atomicAdd(&sDeg[db.x & 255], 1);
  atomicAdd(&sDeg[db.y & 255], 1);
  atomicAdd(&sDeg[db.z & 255], 1);
  atomicAdd(&sDeg[db.w & 255], 1);

  // ---- P1: xw dot (consumes x as it arrives); pin fragments for P5
  #pragma unroll
  for (int r = 0; r < 8; ++r) {
    float acc = q0[r].x*wa.x + q0[r].y*wa.y + q0[r].z*wa.z + q0[r].w*wa.w
              + q1[r].x*wb.x + q1[r].y*wb.y + q1[r].z*wb.z + q1[r].w*wb.w;
    KEEP4(q0[r]);
    KEEP4(q1[r]);
    acc += __shfl_xor(acc, 1);          // DPP within 16-lane group
    acc += __shfl_xor(acc, 2);
    acc += __shfl_xor(acc, 4);
    acc += __shfl_xor(acc, 8);
    if (j == 0) sXW[r * 32 + wave * 4 + sub] = acc;
  }
  __syncthreads();                                      // B2 (deg + xw done)

  // ---- P3: score atomics (rsqrt on the fly; self term by owner)
  if (tid < NPER) {
    float dv = rsqrtf((float)sDeg[tid]);
    atomicAdd(&sScore[tid], sXW[tid] * dv * dv);        // self-loop term
  }
  {
    int s0 = sa.x & 255, d0 = da.x & 255;
    int s1 = sa.y & 255, d1 = da.y & 255;
    int s2 = sa.z & 255, d2 = da.z & 255;
    int s3 = sa.w & 255, d3 = da.w & 255;
    int s4 = sb.x & 255, d4 = db.x & 255;
    int s5 = sb.y & 255, d5 = db.y & 255;
    int s6 = sb.z & 255, d6 = db.z & 255;
    int s7 = sb.w & 255, d7 = db.w & 255;
    atomicAdd(&sScore[d0], sXW[s0] * rsqrtf((float)sDeg[s0]) * rsqrtf((float)sDeg[d0]));
    atomicAdd(&sScore[d1], sXW[s1] * rsqrtf((float)sDeg[s1]) * rsqrtf((float)sDeg[d1]));
    atomicAdd(&sScore[d2], sXW[s2] * rsqrtf((float)sDeg[s2]) * rsqrtf((float)sDeg[d2]));
    atomicAdd(&sScore[d3], sXW[s3] * rsqrtf((float)sDeg[s3]) * rsqrtf((float)sDeg[d3]));
    atomicAdd(&sScore[d4], sXW[s4] * rsqrtf((float)sDeg[s4]) * rsqrtf((float)sDeg[d4]));
    atomicAdd(&sScore[d5], sXW[s5] * rsqrtf((float)sDeg[s5]) * rsqrtf((float)sDeg[d5]));
    atomicAdd(&sScore[d6], sXW[s6] * rsqrtf((float)sDeg[s6]) * rsqrtf((float)sDeg[d6]));
    atomicAdd(&sScore[d7], sXW[s7] * rsqrtf((float)sDeg[s7]) * rsqrtf((float)sDeg[d7]));
  }
  __syncthreads();                                      // B4 (scores final)

  // ---- P4: stable top-K rank + (owners) gate, same phase
  {
    int node = tid & 255;
    int seg  = tid >> 8;
    float s_i = sScore[node];
    if (tid < NPER) sGate[tid] = tanhf(s_i + gcn_b[0]); // own score == s_i
    int base = seg * 32;
    int part = 0;
    #pragma unroll 8
    for (int t = 0; t < 32; ++t) {
      float4 v = sScore4[base + t];
      int jj = (base + t) * 4;
      part += (v.x > s_i) || (v.x == s_i && (jj + 0) < node);
      part += (v.y > s_i) || (v.y == s_i && (jj + 1) < node);
      part += (v.z > s_i) || (v.z == s_i && (jj + 2) < node);
      part += (v.w > s_i) || (v.w == s_i && (jj + 3) < node);
    }
    atomicAdd(&sRank[node], part);
  }
  __syncthreads();                                      // B5 (ranks + gates final)

  // ---- P5: gated mean/max pool from pinned regs -> LDS atomic accumulators
  float su0=0,su1=0,su2=0,su3=0,su4=0,su5=0,su6=0,su7=0;
  float mx0=-INFINITY,mx1=-INFINITY,mx2=-INFINITY,mx3=-INFINITY;
  float mx4=-INFINITY,mx5=-INFINITY,mx6=-INFINITY,mx7=-INFINITY;
  #pragma unroll
  for (int r = 0; r < 8; ++r) {
    int nd = r * 32 + wave * 4 + sub;
    int rk = sRank[nd];                 // 4-addr broadcast
    float gt = sGate[nd];
    bool kp = rk < KK;
    float g1 = kp ? gt : 0.0f;
    float fb = kp ? 0.0f : INFINITY;
    float a;
    a = q0[r].x * g1; su0 += a; mx0 = fmaxf(mx0, a - fb);
    a = q0[r].y * g1; su1 += a; mx1 = fmaxf(mx1, a - fb);
    a = q0[r].z * g1; su2 += a; mx2 = fmaxf(mx2, a - fb);
    a = q0[r].w * g1; su3 += a; mx3 = fmaxf(mx3, a - fb);
    a = q1[r].x * g1; su4 += a; mx4 = fmaxf(mx4, a - fb);
    a = q1[r].y * g1; su5 += a; mx5 = fmaxf(mx5, a - fb);
    a = q1[r].z * g1; su6 += a; mx6 = fmaxf(mx6, a - fb);
    a = q1[r].w * g1; su7 += a; mx7 = fmaxf(mx7, a - fb);
  }
  #define RED_S(v) v += __shfl_xor(v,16); v += __shfl_xor(v,32);
  #define RED_M(v) v = fmaxf(v,__shfl_xor(v,16)); v = fmaxf(v,__shfl_xor(v,32));
  RED_S(su0) RED_S(su1) RED_S(su2) RED_S(su3)
  RED_S(su4) RED_S(su5) RED_S(su6) RED_S(su7)
  RED_M(mx0) RED_M(mx1) RED_M(mx2) RED_M(mx3)
  RED_M(mx4) RED_M(mx5) RED_M(mx6) RED_M(mx7)
  if (sub == 0) {                       // 16 lanes (j=0..15) per wave
    atomicAdd(&sMean[4*j+0], su0);
    atomicAdd(&sMean[4*j+1], su1);
    atomicAdd(&sMean[4*j+2], su2);
    atomicAdd(&sMean[4*j+3], su3);
    atomicAdd(&sMean[64+4*j+0], su4);
    atomicAdd(&sMean[64+4*j+1], su5);
    atomicAdd(&sMean[64+4*j+2], su6);
    atomicAdd(&sMean[64+4*j+3], su7);
    atomicMax(&sMaxK[4*j+0], fkey(mx0));
    atomicMax(&sMaxK[4*j+1], fkey(mx1));
    atomicMax(&sMaxK[4*j+2], fkey(mx2));
    atomicMax(&sMaxK[4*j+3], fkey(mx3));
    atomicMax(&sMaxK[64+4*j+0], fkey(mx4));
    atomicMax(&sMaxK[64+4*j+1], fkey(mx5));
    atomicMax(&sMaxK[64+4*j+2], fkey(mx6));
    atomicMax(&sMaxK[64+4*j+3], fkey(mx7));
  }
  __syncthreads();                                      // B8 (pools final)

  // ---- P6: out = [mean||max] @ lin_w, accumulated via LDS atomics
  const float2* lw2 = (const float2*)lin_w;
  const float inv = 1.0f / KK;
  float a0 = 0.f, a1 = 0.f;
  if (wave < 4) {                       // mean half: readout[0..127]
    #pragma unroll
    for (int t = 0; t < 16; ++t) {
      int k2 = wave * 16 + t;
      float rvx = sMean[2 * k2]     * inv;
      float rvy = sMean[2 * k2 + 1] * inv;
      float2 p0 = lw2[(2 * k2) * 64 + lane];
      float2 p1 = lw2[(2 * k2 + 1) * 64 + lane];
      a0 += rvx * p0.x + rvy * p1.x;
      a1 += rvx * p0.y + rvy * p1.y;
    }
  } else {                              // max half: readout[128..255]
    #pragma unroll
    for (int t = 0; t < 16; ++t) {
      int k2 = wave * 16 + t;
      int d0 = 2 * k2 - 128;
      float rvx = funkey(sMaxK[d0]);
      float rvy = funkey(sMaxK[d0 + 1]);
      float2 p0 = lw2[(2 * k2) * 64 + lane];
      float2 p1 = lw2[(2 * k2 + 1) * 64 + lane];
      a0 += rvx * p0.x + rvy * p1.x;
      a1 += rvx * p0.y + rvy * p1.y;
    }
  }
  atomicAdd(&sOut[2 * lane],     a0);
  atomicAdd(&sOut[2 * lane + 1], a1);
  __syncthreads();                                      // B9
  if (tid < 64) {
    float2 bb = ((const float2*)lin_b)[tid];
    ((float2*)out)[(size_t)g * 64 + tid] =
        make_float2(sOut[2 * tid] + bb.x, sOut[2 * tid + 1] + bb.y);
  }
}

extern "C" void kernel_launch(void* const* d_in, const int* in_sizes, int n_in,
                              void* d_out, int out_size, void* d_ws, size_t ws_size,
                              hipStream_t stream) {
  const float* x  = (const float*)d_in[0];
  // d_in[1] = graph_indicator (unused: equal-size contiguous graphs)
  const int*   ei = (const int*)d_in[2];
  const float* gw = (const float*)d_in[3];
  const float* gb = (const float*)d_in[4];
  const float* lw = (const float*)d_in[5];
  const float* lb = (const float*)d_in[6];
  float* out = (float*)d_out;
  const int E = in_sizes[2] / 2;       // edge_index is [2, E]
  sag_fused<<<NG, NT, 0, stream>>>(x, ei, ei + E, gw, gb, lw, lb, out);
}